// Round 3
// baseline (818.479 us; speedup 1.0000x reference)
//
#include <hip/hip_runtime.h>

#define HIDDEN 2048
#define INTER  5632
#define TOKENS 4096

#define BM 128
#define BN 128
#define BK 64

using bf16x8 = __attribute__((ext_vector_type(8))) __bf16;
using f32x4  = __attribute__((ext_vector_type(4))) float;

// fp32 -> bf16 round-to-nearest-even
__device__ __forceinline__ unsigned short f2bf(float f) {
    unsigned int u = __float_as_uint(f);
    u += 0x7FFFu + ((u >> 16) & 1u);
    return (unsigned short)(u >> 16);
}

// ---------------- fused prep: cast x + dequant 3 weight mats ----------------
__global__ __launch_bounds__(256) void prep_kernel(
        const float* __restrict__ x, unsigned short* __restrict__ xb,
        const int* __restrict__ ig, const float* __restrict__ cbg,
        const float* __restrict__ sg, unsigned short* __restrict__ wg,
        const int* __restrict__ iu, const float* __restrict__ cbu,
        const float* __restrict__ su, unsigned short* __restrict__ wu,
        const int* __restrict__ idn, const float* __restrict__ cbd,
        const float* __restrict__ sd, unsigned short* __restrict__ wd) {
    int b = blockIdx.x;
    if (b < 4096) {
        int t = b * 256 + threadIdx.x;
        const float4* x4 = (const float4*)x;
        float4 a = x4[2 * t];
        float4 c = x4[2 * t + 1];
        uint4 o;
        o.x = f2bf(a.x) | ((unsigned int)f2bf(a.y) << 16);
        o.y = f2bf(a.z) | ((unsigned int)f2bf(a.w) << 16);
        o.z = f2bf(c.x) | ((unsigned int)f2bf(c.y) << 16);
        o.w = f2bf(c.z) | ((unsigned int)f2bf(c.w) << 16);
        ((uint4*)xb)[t] = o;
        return;
    }
    const int* idx; const float* cb; const float* scale; unsigned short* w; int ncol8;
    if (b < 4096 + 5632)      { b -= 4096;         idx = ig;  cb = cbg; scale = sg; w = wg; ncol8 = HIDDEN / 8; }
    else if (b < 4096 + 11264){ b -= 4096 + 5632;  idx = iu;  cb = cbu; scale = su; w = wu; ncol8 = HIDDEN / 8; }
    else                      { b -= 4096 + 11264; idx = idn; cb = cbd; scale = sd; w = wd; ncol8 = INTER / 8; }
    int t = b * 256 + threadIdx.x;
    int row = t / ncol8;
    int id = idx[t];
    float s = scale[row];
    const float4* c4 = (const float4*)(cb + ((size_t)id << 3));
    float4 a = c4[0];
    float4 c = c4[1];
    uint4 o;
    o.x = f2bf(a.x * s) | ((unsigned int)f2bf(a.y * s) << 16);
    o.y = f2bf(a.z * s) | ((unsigned int)f2bf(a.w * s) << 16);
    o.z = f2bf(c.x * s) | ((unsigned int)f2bf(c.y * s) << 16);
    o.w = f2bf(c.z * s) | ((unsigned int)f2bf(c.w * s) << 16);
    ((uint4*)w)[t] = o;
}

// XOR-swizzled LDS layout: physical 16B chunk p of row r holds logical chunk
// p ^ (r & 7).  Staging LDS dest stays lane-contiguous (global_load_lds
// constraint); the swizzle is applied to the GLOBAL source column instead.
// R2 verified: SQ_LDS_BANK_CONFLICT == 0 with this scheme.

// ---------------- GEMM1: H = silu(X Wg^T) * (X Wu^T), bf16 out ----------------
// launch_bounds(256,3): 3 blocks/CU (LDS 48KB*3=144<=160KB) so one block's
// LDS-read burst overlaps another's MFMA burst (phases are barrier-locked
// within a block but free across blocks).
__global__ __launch_bounds__(256, 3) void gemm1_kernel(const unsigned short* __restrict__ X,
                                                       const unsigned short* __restrict__ Wg,
                                                       const unsigned short* __restrict__ Wu,
                                                       unsigned short* __restrict__ H) {
    __shared__ unsigned short As[BM * BK];
    __shared__ unsigned short Bgs[BN * BK];
    __shared__ unsigned short Bus[BN * BK];

    const int tid  = threadIdx.x;
    const int lane = tid & 63;
    const int wave = tid >> 6;
    const int m0 = blockIdx.x * BM;
    const int n0 = blockIdx.y * BN;

    const int srow = tid >> 3;
    const int scol = (tid & 7) << 3;                       // LDS phys halfword offset
    const int gcol = (((tid & 7) ^ (srow & 7))) << 3;      // swizzled global halfword offset

    const int wr = wave >> 1;
    const int wc = wave & 1;
    const int ln15 = lane & 15;
    const int lq = lane >> 4;
    const int swr = ln15 & 7;

    f32x4 accg[4][4], accu[4][4];
    const f32x4 z = {0.f, 0.f, 0.f, 0.f};
    for (int i = 0; i < 4; ++i)
        for (int j = 0; j < 4; ++j) { accg[i][j] = z; accu[i][j] = z; }

    for (int kt = 0; kt < HIDDEN / BK; ++kt) {
        const int k0 = kt * BK;
        __syncthreads();
#pragma unroll
        for (int i = 0; i < 4; ++i) {
            const int r = i * 32 + srow;
            __builtin_amdgcn_global_load_lds(
                (__attribute__((address_space(1))) void*)(X + (size_t)(m0 + r) * HIDDEN + k0 + gcol),
                (__attribute__((address_space(3))) void*)(As + r * BK + scol), 16, 0, 0);
            __builtin_amdgcn_global_load_lds(
                (__attribute__((address_space(1))) void*)(Wg + (size_t)(n0 + r) * HIDDEN + k0 + gcol),
                (__attribute__((address_space(3))) void*)(Bgs + r * BK + scol), 16, 0, 0);
            __builtin_amdgcn_global_load_lds(
                (__attribute__((address_space(1))) void*)(Wu + (size_t)(n0 + r) * HIDDEN + k0 + gcol),
                (__attribute__((address_space(3))) void*)(Bus + r * BK + scol), 16, 0, 0);
        }
        __syncthreads();
#pragma unroll
        for (int ks = 0; ks < 2; ++ks) {
            bf16x8 af[4], bg[4], bu[4];
            const int pofs = (((ks * 4 + lq) ^ swr)) << 3;
#pragma unroll
            for (int im = 0; im < 4; ++im)
                af[im] = *(const bf16x8*)(As + (wr * 64 + im * 16 + ln15) * BK + pofs);
#pragma unroll
            for (int in = 0; in < 4; ++in) {
                bg[in] = *(const bf16x8*)(Bgs + (wc * 64 + in * 16 + ln15) * BK + pofs);
                bu[in] = *(const bf16x8*)(Bus + (wc * 64 + in * 16 + ln15) * BK + pofs);
            }
#pragma unroll
            for (int im = 0; im < 4; ++im)
#pragma unroll
                for (int in = 0; in < 4; ++in) {
                    accg[im][in] = __builtin_amdgcn_mfma_f32_16x16x32_bf16(af[im], bg[in], accg[im][in], 0, 0, 0);
                    accu[im][in] = __builtin_amdgcn_mfma_f32_16x16x32_bf16(af[im], bu[in], accu[im][in], 0, 0, 0);
                }
        }
    }

#pragma unroll
    for (int im = 0; im < 4; ++im)
#pragma unroll
        for (int in = 0; in < 4; ++in) {
            const int row = m0 + wr * 64 + im * 16 + lq * 4;
            const int col = n0 + wc * 64 + in * 16 + ln15;
#pragma unroll
            for (int r = 0; r < 4; ++r) {
                float g = accg[im][in][r];
                float u = accu[im][in][r];
                float h = g * (1.0f / (1.0f + __expf(-g))) * u;
                H[(size_t)(row + r) * INTER + col] = f2bf(h);
            }
        }
}

// ---------------- GEMM2: Out = H Wd^T, fp32 out ----------------
// launch_bounds(256,4): LDS 32KB -> up to 5 blocks/CU; VGPR cap 128 >= use.
__global__ __launch_bounds__(256, 4) void gemm2_kernel(const unsigned short* __restrict__ Hin,
                                                       const unsigned short* __restrict__ Wd,
                                                       float* __restrict__ Out) {
    __shared__ unsigned short As[BM * BK];
    __shared__ unsigned short Bs[BN * BK];

    const int tid  = threadIdx.x;
    const int lane = tid & 63;
    const int wave = tid >> 6;
    const int m0 = blockIdx.x * BM;
    const int n0 = blockIdx.y * BN;

    const int srow = tid >> 3;
    const int scol = (tid & 7) << 3;
    const int gcol = (((tid & 7) ^ (srow & 7))) << 3;

    const int wr = wave >> 1;
    const int wc = wave & 1;
    const int ln15 = lane & 15;
    const int lq = lane >> 4;
    const int swr = ln15 & 7;

    f32x4 acc[4][4];
    const f32x4 z = {0.f, 0.f, 0.f, 0.f};
    for (int i = 0; i < 4; ++i)
        for (int j = 0; j < 4; ++j) acc[i][j] = z;

    for (int kt = 0; kt < INTER / BK; ++kt) {
        const int k0 = kt * BK;
        __syncthreads();
#pragma unroll
        for (int i = 0; i < 4; ++i) {
            const int r = i * 32 + srow;
            __builtin_amdgcn_global_load_lds(
                (__attribute__((address_space(1))) void*)(Hin + (size_t)(m0 + r) * INTER + k0 + gcol),
                (__attribute__((address_space(3))) void*)(As + r * BK + scol), 16, 0, 0);
            __builtin_amdgcn_global_load_lds(
                (__attribute__((address_space(1))) void*)(Wd + (size_t)(n0 + r) * INTER + k0 + gcol),
                (__attribute__((address_space(3))) void*)(Bs + r * BK + scol), 16, 0, 0);
        }
        __syncthreads();
#pragma unroll
        for (int ks = 0; ks < 2; ++ks) {
            bf16x8 af[4], bf[4];
            const int pofs = (((ks * 4 + lq) ^ swr)) << 3;
#pragma unroll
            for (int im = 0; im < 4; ++im)
                af[im] = *(const bf16x8*)(As + (wr * 64 + im * 16 + ln15) * BK + pofs);
#pragma unroll
            for (int in = 0; in < 4; ++in)
                bf[in] = *(const bf16x8*)(Bs + (wc * 64 + in * 16 + ln15) * BK + pofs);
#pragma unroll
            for (int im = 0; im < 4; ++im)
#pragma unroll
                for (int in = 0; in < 4; ++in)
                    acc[im][in] = __builtin_amdgcn_mfma_f32_16x16x32_bf16(af[im], bf[in], acc[im][in], 0, 0, 0);
        }
    }

#pragma unroll
    for (int im = 0; im < 4; ++im)
#pragma unroll
        for (int in = 0; in < 4; ++in) {
            const int row = m0 + wr * 64 + im * 16 + lq * 4;
            const int col = n0 + wc * 64 + in * 16 + ln15;
#pragma unroll
            for (int r = 0; r < 4; ++r)
                Out[(size_t)(row + r) * HIDDEN + col] = acc[im][in][r];
        }
}

extern "C" void kernel_launch(void* const* d_in, const int* in_sizes, int n_in,
                              void* d_out, int out_size, void* d_ws, size_t ws_size,
                              hipStream_t stream) {
    (void)in_sizes; (void)n_in; (void)out_size; (void)ws_size;

    const float* x   = (const float*)d_in[0];
    const float* cbg = (const float*)d_in[1];
    const int*   ig  = (const int*)d_in[2];
    const float* sg  = (const float*)d_in[3];
    const float* cbu = (const float*)d_in[4];
    const int*   iu  = (const int*)d_in[5];
    const float* su  = (const float*)d_in[6];
    const float* cbd = (const float*)d_in[7];
    const int*   idn = (const int*)d_in[8];
    const float* sd  = (const float*)d_in[9];
    float* out = (float*)d_out;

    char* p = (char*)d_ws;
    unsigned short* Xb = (unsigned short*)p; p += (size_t)TOKENS * HIDDEN * 2;
    unsigned short* Wg = (unsigned short*)p; p += (size_t)INTER * HIDDEN * 2;
    unsigned short* Wu = (unsigned short*)p; p += (size_t)INTER * HIDDEN * 2;
    unsigned short* Wd = (unsigned short*)p; p += (size_t)HIDDEN * INTER * 2;
    unsigned short* H  = (unsigned short*)p; p += (size_t)TOKENS * INTER * 2;

    prep_kernel<<<dim3(4096 + 3 * 5632), dim3(256), 0, stream>>>(
        x, Xb, ig, cbg, sg, Wg, iu, cbu, su, Wu, idn, cbd, sd, Wd);

    gemm1_kernel<<<dim3(TOKENS / BM, INTER / BN), dim3(256), 0, stream>>>(Xb, Wg, Wu, H);
    gemm2_kernel<<<dim3(TOKENS / BM, HIDDEN / BN), dim3(256), 0, stream>>>(H, Wd, out);
}

// Round 4
// 492.771 us; speedup vs baseline: 1.6610x; 1.6610x over previous
//
#include <hip/hip_runtime.h>

#define HIDDEN 2048
#define INTER  5632
#define TOKENS 4096

#define BM 128
#define BN 128
#define BK 32          // half-K tiles so a DOUBLE buffer fits 2 blocks/CU

using bf16x8 = __attribute__((ext_vector_type(8))) __bf16;
using f32x4  = __attribute__((ext_vector_type(4))) float;

// fp32 -> bf16 round-to-nearest-even
__device__ __forceinline__ unsigned short f2bf(float f) {
    unsigned int u = __float_as_uint(f);
    u += 0x7FFFu + ((u >> 16) & 1u);
    return (unsigned short)(u >> 16);
}

#define GLDS(gptr, lptr) \
    __builtin_amdgcn_global_load_lds((__attribute__((address_space(1))) void*)(gptr), \
                                     (__attribute__((address_space(3))) void*)(lptr), 16, 0, 0)

// ---------------- fused prep: cast x + dequant 3 weight mats ----------------
__global__ __launch_bounds__(256) void prep_kernel(
        const float* __restrict__ x, unsigned short* __restrict__ xb,
        const int* __restrict__ ig, const float* __restrict__ cbg,
        const float* __restrict__ sg, unsigned short* __restrict__ wg,
        const int* __restrict__ iu, const float* __restrict__ cbu,
        const float* __restrict__ su, unsigned short* __restrict__ wu,
        const int* __restrict__ idn, const float* __restrict__ cbd,
        const float* __restrict__ sd, unsigned short* __restrict__ wd) {
    int b = blockIdx.x;
    if (b < 4096) {
        int t = b * 256 + threadIdx.x;
        const float4* x4 = (const float4*)x;
        float4 a = x4[2 * t];
        float4 c = x4[2 * t + 1];
        uint4 o;
        o.x = f2bf(a.x) | ((unsigned int)f2bf(a.y) << 16);
        o.y = f2bf(a.z) | ((unsigned int)f2bf(a.w) << 16);
        o.z = f2bf(c.x) | ((unsigned int)f2bf(c.y) << 16);
        o.w = f2bf(c.z) | ((unsigned int)f2bf(c.w) << 16);
        ((uint4*)xb)[t] = o;
        return;
    }
    const int* idx; const float* cb; const float* scale; unsigned short* w; int ncol8;
    if (b < 4096 + 5632)      { b -= 4096;         idx = ig;  cb = cbg; scale = sg; w = wg; ncol8 = HIDDEN / 8; }
    else if (b < 4096 + 11264){ b -= 4096 + 5632;  idx = iu;  cb = cbu; scale = su; w = wu; ncol8 = HIDDEN / 8; }
    else                      { b -= 4096 + 11264; idx = idn; cb = cbd; scale = sd; w = wd; ncol8 = INTER / 8; }
    int t = b * 256 + threadIdx.x;
    int row = t / ncol8;
    int id = idx[t];
    float s = scale[row];
    const float4* c4 = (const float4*)(cb + ((size_t)id << 3));
    float4 a = c4[0];
    float4 c = c4[1];
    uint4 o;
    o.x = f2bf(a.x * s) | ((unsigned int)f2bf(a.y * s) << 16);
    o.y = f2bf(a.z * s) | ((unsigned int)f2bf(a.w * s) << 16);
    o.z = f2bf(c.x * s) | ((unsigned int)f2bf(c.y * s) << 16);
    o.w = f2bf(c.z * s) | ((unsigned int)f2bf(c.w * s) << 16);
    ((uint4*)w)[t] = o;
}

// BK=32 XOR swizzle: rows are 4 chunks of 16B; phys chunk p of row r holds
// logical chunk p ^ ((r>>1)&3).  Swizzle applied on the GLOBAL source so the
// glds LDS dest stays lane-contiguous.  Per 16-lane group accesses spread
// across 8 4-bank slots 2-way (free) — mirror of the R2-verified scheme.

// ---------------- GEMM1: H = silu(X Wg^T) * (X Wu^T), bf16 out ----------------
// Double-buffered: stage(kt+1) issued AFTER the barrier, so the next
// barrier's vmcnt(0) drain happens after a full compute phase.
// launch_bounds(256,2): unified VGPR+AGPR budget 256/wave; acc alone is 128.
__global__ __launch_bounds__(256, 2) void gemm1_kernel(const unsigned short* __restrict__ X,
                                                       const unsigned short* __restrict__ Wg,
                                                       const unsigned short* __restrict__ Wu,
                                                       unsigned short* __restrict__ H) {
    __shared__ unsigned short As[2 * BM * BK];
    __shared__ unsigned short Bgs[2 * BN * BK];
    __shared__ unsigned short Bus[2 * BN * BK];

    const int tid  = threadIdx.x;
    const int lane = tid & 63;
    const int wave = tid >> 6;
    const int m0 = blockIdx.x * BM;
    const int n0 = blockIdx.y * BN;

    // staging: 256 threads cover 64 rows x 4 chunks; 2 issues per matrix.
    const int srow = tid >> 2;                                   // 0..63
    const int scol = (tid & 3) << 3;                             // LDS phys chunk
    const int gcol = (((tid & 3) ^ ((srow >> 1) & 3))) << 3;     // swizzled global chunk

    const int wr = wave >> 1;
    const int wc = wave & 1;
    const int ln15 = lane & 15;
    const int lq = lane >> 4;
    const int pofs = ((lq ^ ((ln15 >> 1) & 3))) << 3;            // swizzled frag chunk

    const size_t gA0 = (size_t)(m0 + srow) * HIDDEN + gcol;
    const size_t gB0 = (size_t)(n0 + srow) * HIDDEN + gcol;
    const int ldsOfs = srow * BK + scol;

    f32x4 accg[4][4], accu[4][4];
    const f32x4 z = {0.f, 0.f, 0.f, 0.f};
    for (int i = 0; i < 4; ++i)
        for (int j = 0; j < 4; ++j) { accg[i][j] = z; accu[i][j] = z; }

    const int NT = HIDDEN / BK;  // 64

    // prologue: stage kt=0 into buffer 0
    {
        GLDS(X  + gA0,            As  + ldsOfs);
        GLDS(X  + gA0 + 64*HIDDEN, As  + ldsOfs + 64*BK);
        GLDS(Wg + gB0,            Bgs + ldsOfs);
        GLDS(Wg + gB0 + 64*HIDDEN, Bgs + ldsOfs + 64*BK);
        GLDS(Wu + gB0,            Bus + ldsOfs);
        GLDS(Wu + gB0 + 64*HIDDEN, Bus + ldsOfs + 64*BK);
    }

    for (int kt = 0; kt < NT; ++kt) {
        __syncthreads();   // drains stage(kt) (vmcnt) + prev reads (lgkmcnt)
        if (kt + 1 < NT) {
            const int nb = (kt + 1) & 1;
            const size_t k1 = (size_t)(kt + 1) * BK;
            GLDS(X  + gA0 + k1,             As  + nb*BM*BK + ldsOfs);
            GLDS(X  + gA0 + k1 + 64*HIDDEN, As  + nb*BM*BK + ldsOfs + 64*BK);
            GLDS(Wg + gB0 + k1,             Bgs + nb*BN*BK + ldsOfs);
            GLDS(Wg + gB0 + k1 + 64*HIDDEN, Bgs + nb*BN*BK + ldsOfs + 64*BK);
            GLDS(Wu + gB0 + k1,             Bus + nb*BN*BK + ldsOfs);
            GLDS(Wu + gB0 + k1 + 64*HIDDEN, Bus + nb*BN*BK + ldsOfs + 64*BK);
        }
        const unsigned short* Ab = As  + (kt & 1) * BM * BK;
        const unsigned short* Gb = Bgs + (kt & 1) * BN * BK;
        const unsigned short* Ub = Bus + (kt & 1) * BN * BK;

        bf16x8 af[4], bg[4], bu[4];
#pragma unroll
        for (int im = 0; im < 4; ++im)
            af[im] = *(const bf16x8*)(Ab + (wr * 64 + im * 16 + ln15) * BK + pofs);
#pragma unroll
        for (int in = 0; in < 4; ++in) {
            bg[in] = *(const bf16x8*)(Gb + (wc * 64 + in * 16 + ln15) * BK + pofs);
            bu[in] = *(const bf16x8*)(Ub + (wc * 64 + in * 16 + ln15) * BK + pofs);
        }
#pragma unroll
        for (int im = 0; im < 4; ++im)
#pragma unroll
            for (int in = 0; in < 4; ++in) {
                accg[im][in] = __builtin_amdgcn_mfma_f32_16x16x32_bf16(af[im], bg[in], accg[im][in], 0, 0, 0);
                accu[im][in] = __builtin_amdgcn_mfma_f32_16x16x32_bf16(af[im], bu[in], accu[im][in], 0, 0, 0);
            }
    }

#pragma unroll
    for (int im = 0; im < 4; ++im)
#pragma unroll
        for (int in = 0; in < 4; ++in) {
            const int row = m0 + wr * 64 + im * 16 + lq * 4;
            const int col = n0 + wc * 64 + in * 16 + ln15;
#pragma unroll
            for (int r = 0; r < 4; ++r) {
                float g = accg[im][in][r];
                float u = accu[im][in][r];
                float h = g * (1.0f / (1.0f + __expf(-g))) * u;
                H[(size_t)(row + r) * INTER + col] = f2bf(h);
            }
        }
}

// ---------------- GEMM2: Out = H Wd^T, fp32 out ----------------
__global__ __launch_bounds__(256, 2) void gemm2_kernel(const unsigned short* __restrict__ Hin,
                                                       const unsigned short* __restrict__ Wd,
                                                       float* __restrict__ Out) {
    __shared__ unsigned short As[2 * BM * BK];
    __shared__ unsigned short Bs[2 * BN * BK];

    const int tid  = threadIdx.x;
    const int lane = tid & 63;
    const int wave = tid >> 6;
    const int m0 = blockIdx.x * BM;
    const int n0 = blockIdx.y * BN;

    const int srow = tid >> 2;
    const int scol = (tid & 3) << 3;
    const int gcol = (((tid & 3) ^ ((srow >> 1) & 3))) << 3;

    const int wr = wave >> 1;
    const int wc = wave & 1;
    const int ln15 = lane & 15;
    const int lq = lane >> 4;
    const int pofs = ((lq ^ ((ln15 >> 1) & 3))) << 3;

    const size_t gA0 = (size_t)(m0 + srow) * INTER + gcol;
    const size_t gB0 = (size_t)(n0 + srow) * INTER + gcol;
    const int ldsOfs = srow * BK + scol;

    f32x4 acc[4][4];
    const f32x4 z = {0.f, 0.f, 0.f, 0.f};
    for (int i = 0; i < 4; ++i)
        for (int j = 0; j < 4; ++j) acc[i][j] = z;

    const int NT = INTER / BK;  // 176

    {
        GLDS(Hin + gA0,            As + ldsOfs);
        GLDS(Hin + gA0 + 64*INTER, As + ldsOfs + 64*BK);
        GLDS(Wd  + gB0,            Bs + ldsOfs);
        GLDS(Wd  + gB0 + 64*INTER, Bs + ldsOfs + 64*BK);
    }

    for (int kt = 0; kt < NT; ++kt) {
        __syncthreads();
        if (kt + 1 < NT) {
            const int nb = (kt + 1) & 1;
            const size_t k1 = (size_t)(kt + 1) * BK;
            GLDS(Hin + gA0 + k1,            As + nb*BM*BK + ldsOfs);
            GLDS(Hin + gA0 + k1 + 64*INTER, As + nb*BM*BK + ldsOfs + 64*BK);
            GLDS(Wd  + gB0 + k1,            Bs + nb*BN*BK + ldsOfs);
            GLDS(Wd  + gB0 + k1 + 64*INTER, Bs + nb*BN*BK + ldsOfs + 64*BK);
        }
        const unsigned short* Ab = As + (kt & 1) * BM * BK;
        const unsigned short* Bb = Bs + (kt & 1) * BN * BK;

        bf16x8 af[4], bf[4];
#pragma unroll
        for (int im = 0; im < 4; ++im)
            af[im] = *(const bf16x8*)(Ab + (wr * 64 + im * 16 + ln15) * BK + pofs);
#pragma unroll
        for (int in = 0; in < 4; ++in)
            bf[in] = *(const bf16x8*)(Bb + (wc * 64 + in * 16 + ln15) * BK + pofs);
#pragma unroll
        for (int im = 0; im < 4; ++im)
#pragma unroll
            for (int in = 0; in < 4; ++in)
                acc[im][in] = __builtin_amdgcn_mfma_f32_16x16x32_bf16(af[im], bf[in], acc[im][in], 0, 0, 0);
    }

#pragma unroll
    for (int im = 0; im < 4; ++im)
#pragma unroll
        for (int in = 0; in < 4; ++in) {
            const int row = m0 + wr * 64 + im * 16 + lq * 4;
            const int col = n0 + wc * 64 + in * 16 + ln15;
#pragma unroll
            for (int r = 0; r < 4; ++r)
                Out[(size_t)(row + r) * HIDDEN + col] = acc[im][in][r];
        }
}

extern "C" void kernel_launch(void* const* d_in, const int* in_sizes, int n_in,
                              void* d_out, int out_size, void* d_ws, size_t ws_size,
                              hipStream_t stream) {
    (void)in_sizes; (void)n_in; (void)out_size; (void)ws_size;

    const float* x   = (const float*)d_in[0];
    const float* cbg = (const float*)d_in[1];
    const int*   ig  = (const int*)d_in[2];
    const float* sg  = (const float*)d_in[3];
    const float* cbu = (const float*)d_in[4];
    const int*   iu  = (const int*)d_in[5];
    const float* su  = (const float*)d_in[6];
    const float* cbd = (const float*)d_in[7];
    const int*   idn = (const int*)d_in[8];
    const float* sd  = (const float*)d_in[9];
    float* out = (float*)d_out;

    char* p = (char*)d_ws;
    unsigned short* Xb = (unsigned short*)p; p += (size_t)TOKENS * HIDDEN * 2;
    unsigned short* Wg = (unsigned short*)p; p += (size_t)INTER * HIDDEN * 2;
    unsigned short* Wu = (unsigned short*)p; p += (size_t)INTER * HIDDEN * 2;
    unsigned short* Wd = (unsigned short*)p; p += (size_t)HIDDEN * INTER * 2;
    unsigned short* H  = (unsigned short*)p; p += (size_t)TOKENS * INTER * 2;

    prep_kernel<<<dim3(4096 + 3 * 5632), dim3(256), 0, stream>>>(
        x, Xb, ig, cbg, sg, Wg, iu, cbu, su, Wu, idn, cbd, sd, Wd);

    gemm1_kernel<<<dim3(TOKENS / BM, INTER / BN), dim3(256), 0, stream>>>(Xb, Wg, Wu, H);
    gemm2_kernel<<<dim3(TOKENS / BM, HIDDEN / BN), dim3(256), 0, stream>>>(H, Wd, out);
}

// Round 5
// 381.951 us; speedup vs baseline: 2.1429x; 1.2901x over previous
//
#include <hip/hip_runtime.h>

#define HIDDEN 2048
#define INTER  5632
#define TOKENS 4096

#define BM 128
#define BN 128
#define BK 64
#define GROUP_N 4   // rasterization: 32-m x 4-n superblocks for L2 locality

using bf16x8 = __attribute__((ext_vector_type(8))) __bf16;
using f32x4  = __attribute__((ext_vector_type(4))) float;

// fp32 -> bf16 round-to-nearest-even
__device__ __forceinline__ unsigned short f2bf(float f) {
    unsigned int u = __float_as_uint(f);
    u += 0x7FFFu + ((u >> 16) & 1u);
    return (unsigned short)(u >> 16);
}

#define GLDS(gptr, lptr) \
    __builtin_amdgcn_global_load_lds((__attribute__((address_space(1))) void*)(gptr), \
                                     (__attribute__((address_space(3))) void*)(lptr), 16, 0, 0)

// ---------------- fused prep: cast x + dequant 3 weight mats ----------------
__global__ __launch_bounds__(256) void prep_kernel(
        const float* __restrict__ x, unsigned short* __restrict__ xb,
        const int* __restrict__ ig, const float* __restrict__ cbg,
        const float* __restrict__ sg, unsigned short* __restrict__ wg,
        const int* __restrict__ iu, const float* __restrict__ cbu,
        const float* __restrict__ su, unsigned short* __restrict__ wu,
        const int* __restrict__ idn, const float* __restrict__ cbd,
        const float* __restrict__ sd, unsigned short* __restrict__ wd) {
    int b = blockIdx.x;
    if (b < 4096) {
        int t = b * 256 + threadIdx.x;
        const float4* x4 = (const float4*)x;
        float4 a = x4[2 * t];
        float4 c = x4[2 * t + 1];
        uint4 o;
        o.x = f2bf(a.x) | ((unsigned int)f2bf(a.y) << 16);
        o.y = f2bf(a.z) | ((unsigned int)f2bf(a.w) << 16);
        o.z = f2bf(c.x) | ((unsigned int)f2bf(c.y) << 16);
        o.w = f2bf(c.z) | ((unsigned int)f2bf(c.w) << 16);
        ((uint4*)xb)[t] = o;
        return;
    }
    const int* idx; const float* cb; const float* scale; unsigned short* w; int ncol8;
    if (b < 4096 + 5632)      { b -= 4096;         idx = ig;  cb = cbg; scale = sg; w = wg; ncol8 = HIDDEN / 8; }
    else if (b < 4096 + 11264){ b -= 4096 + 5632;  idx = iu;  cb = cbu; scale = su; w = wu; ncol8 = HIDDEN / 8; }
    else                      { b -= 4096 + 11264; idx = idn; cb = cbd; scale = sd; w = wd; ncol8 = INTER / 8; }
    int t = b * 256 + threadIdx.x;
    int row = t / ncol8;
    int id = idx[t];
    float s = scale[row];
    const float4* c4 = (const float4*)(cb + ((size_t)id << 3));
    float4 a = c4[0];
    float4 c = c4[1];
    uint4 o;
    o.x = f2bf(a.x * s) | ((unsigned int)f2bf(a.y * s) << 16);
    o.y = f2bf(a.z * s) | ((unsigned int)f2bf(a.w * s) << 16);
    o.z = f2bf(c.x * s) | ((unsigned int)f2bf(c.y * s) << 16);
    o.w = f2bf(c.z * s) | ((unsigned int)f2bf(c.w * s) << 16);
    ((uint4*)w)[t] = o;
}

// XOR-swizzled LDS layout (R2-verified: SQ_LDS_BANK_CONFLICT == 0):
// physical 16B chunk p of row r holds logical chunk p ^ (r & 7); swizzle is
// applied on the GLOBAL source so the glds LDS dest stays lane-contiguous.

// group-major block decode: 1D grid -> (mb, nb); GROUP_N n-panels per group
// so each XCD's co-resident blocks share ~4 B-panels (~L2-sized).
__device__ __forceinline__ void decode_block(int bid, int nblocks_n, int* mb, int* nb) {
    int gw = 32 * GROUP_N;             // blocks per full group (TOKENS/BM = 32)
    int group = bid / gw;
    int inb = bid % gw;
    int gn = group * GROUP_N;
    int width = (nblocks_n - gn < GROUP_N) ? (nblocks_n - gn) : GROUP_N;
    *mb = inb / width;
    *nb = gn + inb % width;
}

// ---------------- GEMM1: H = silu(X Wg^T) * (X Wu^T), bf16 out ----------------
// R2 structure: single LDS buffer, 2 barriers/kt; 2 blocks/CU (the unified
// VGPR+AGPR file caps us: 128 acc regs + addressing needs the 256-reg/wave
// budget of 2 waves/EU — (256,3) spilled catastrophically in R3).
__global__ __launch_bounds__(256, 2) void gemm1_kernel(const unsigned short* __restrict__ X,
                                                       const unsigned short* __restrict__ Wg,
                                                       const unsigned short* __restrict__ Wu,
                                                       unsigned short* __restrict__ H) {
    __shared__ unsigned short As[BM * BK];
    __shared__ unsigned short Bgs[BN * BK];
    __shared__ unsigned short Bus[BN * BK];

    const int tid  = threadIdx.x;
    const int lane = tid & 63;
    const int wave = tid >> 6;
    int mb, nb;
    decode_block(blockIdx.x, INTER / BN, &mb, &nb);
    const int m0 = mb * BM;
    const int n0 = nb * BN;

    const int srow = tid >> 3;
    const int scol = (tid & 7) << 3;                       // LDS phys halfword offset
    const int gcol = (((tid & 7) ^ (srow & 7))) << 3;      // swizzled global halfword offset

    const int wr = wave >> 1;
    const int wc = wave & 1;
    const int ln15 = lane & 15;
    const int lq = lane >> 4;
    const int swr = ln15 & 7;

    f32x4 accg[4][4], accu[4][4];
    const f32x4 z = {0.f, 0.f, 0.f, 0.f};
    for (int i = 0; i < 4; ++i)
        for (int j = 0; j < 4; ++j) { accg[i][j] = z; accu[i][j] = z; }

    for (int kt = 0; kt < HIDDEN / BK; ++kt) {
        const int k0 = kt * BK;
        __syncthreads();
#pragma unroll
        for (int i = 0; i < 4; ++i) {
            const int r = i * 32 + srow;
            GLDS(X  + (size_t)(m0 + r) * HIDDEN + k0 + gcol, As  + r * BK + scol);
            GLDS(Wg + (size_t)(n0 + r) * HIDDEN + k0 + gcol, Bgs + r * BK + scol);
            GLDS(Wu + (size_t)(n0 + r) * HIDDEN + k0 + gcol, Bus + r * BK + scol);
        }
        __syncthreads();
#pragma unroll
        for (int ks = 0; ks < 2; ++ks) {
            bf16x8 af[4], bg[4], bu[4];
            const int pofs = (((ks * 4 + lq) ^ swr)) << 3;
#pragma unroll
            for (int im = 0; im < 4; ++im)
                af[im] = *(const bf16x8*)(As + (wr * 64 + im * 16 + ln15) * BK + pofs);
#pragma unroll
            for (int in = 0; in < 4; ++in) {
                bg[in] = *(const bf16x8*)(Bgs + (wc * 64 + in * 16 + ln15) * BK + pofs);
                bu[in] = *(const bf16x8*)(Bus + (wc * 64 + in * 16 + ln15) * BK + pofs);
            }
#pragma unroll
            for (int im = 0; im < 4; ++im)
#pragma unroll
                for (int in = 0; in < 4; ++in) {
                    accg[im][in] = __builtin_amdgcn_mfma_f32_16x16x32_bf16(af[im], bg[in], accg[im][in], 0, 0, 0);
                    accu[im][in] = __builtin_amdgcn_mfma_f32_16x16x32_bf16(af[im], bu[in], accu[im][in], 0, 0, 0);
                }
        }
    }

#pragma unroll
    for (int im = 0; im < 4; ++im)
#pragma unroll
        for (int in = 0; in < 4; ++in) {
            const int row = m0 + wr * 64 + im * 16 + lq * 4;
            const int col = n0 + wc * 64 + in * 16 + ln15;
#pragma unroll
            for (int r = 0; r < 4; ++r) {
                float g = accg[im][in][r];
                float u = accu[im][in][r];
                float h = g * (1.0f / (1.0f + __expf(-g))) * u;
                H[(size_t)(row + r) * INTER + col] = f2bf(h);
            }
        }
}

// ---------------- GEMM2: Out = H Wd^T, fp32 out ----------------
__global__ __launch_bounds__(256, 2) void gemm2_kernel(const unsigned short* __restrict__ Hin,
                                                       const unsigned short* __restrict__ Wd,
                                                       float* __restrict__ Out) {
    __shared__ unsigned short As[BM * BK];
    __shared__ unsigned short Bs[BN * BK];

    const int tid  = threadIdx.x;
    const int lane = tid & 63;
    const int wave = tid >> 6;
    int mb, nb;
    decode_block(blockIdx.x, HIDDEN / BN, &mb, &nb);
    const int m0 = mb * BM;
    const int n0 = nb * BN;

    const int srow = tid >> 3;
    const int scol = (tid & 7) << 3;
    const int gcol = (((tid & 7) ^ (srow & 7))) << 3;

    const int wr = wave >> 1;
    const int wc = wave & 1;
    const int ln15 = lane & 15;
    const int lq = lane >> 4;
    const int swr = ln15 & 7;

    f32x4 acc[4][4];
    const f32x4 z = {0.f, 0.f, 0.f, 0.f};
    for (int i = 0; i < 4; ++i)
        for (int j = 0; j < 4; ++j) acc[i][j] = z;

    for (int kt = 0; kt < INTER / BK; ++kt) {
        const int k0 = kt * BK;
        __syncthreads();
#pragma unroll
        for (int i = 0; i < 4; ++i) {
            const int r = i * 32 + srow;
            GLDS(Hin + (size_t)(m0 + r) * INTER + k0 + gcol, As + r * BK + scol);
            GLDS(Wd  + (size_t)(n0 + r) * INTER + k0 + gcol, Bs + r * BK + scol);
        }
        __syncthreads();
#pragma unroll
        for (int ks = 0; ks < 2; ++ks) {
            bf16x8 af[4], bf[4];
            const int pofs = (((ks * 4 + lq) ^ swr)) << 3;
#pragma unroll
            for (int im = 0; im < 4; ++im)
                af[im] = *(const bf16x8*)(As + (wr * 64 + im * 16 + ln15) * BK + pofs);
#pragma unroll
            for (int in = 0; in < 4; ++in)
                bf[in] = *(const bf16x8*)(Bs + (wc * 64 + in * 16 + ln15) * BK + pofs);
#pragma unroll
            for (int im = 0; im < 4; ++im)
#pragma unroll
                for (int in = 0; in < 4; ++in)
                    acc[im][in] = __builtin_amdgcn_mfma_f32_16x16x32_bf16(af[im], bf[in], acc[im][in], 0, 0, 0);
        }
    }

#pragma unroll
    for (int im = 0; im < 4; ++im)
#pragma unroll
        for (int in = 0; in < 4; ++in) {
            const int row = m0 + wr * 64 + im * 16 + lq * 4;
            const int col = n0 + wc * 64 + in * 16 + ln15;
#pragma unroll
            for (int r = 0; r < 4; ++r)
                Out[(size_t)(row + r) * HIDDEN + col] = acc[im][in][r];
        }
}

extern "C" void kernel_launch(void* const* d_in, const int* in_sizes, int n_in,
                              void* d_out, int out_size, void* d_ws, size_t ws_size,
                              hipStream_t stream) {
    (void)in_sizes; (void)n_in; (void)out_size; (void)ws_size;

    const float* x   = (const float*)d_in[0];
    const float* cbg = (const float*)d_in[1];
    const int*   ig  = (const int*)d_in[2];
    const float* sg  = (const float*)d_in[3];
    const float* cbu = (const float*)d_in[4];
    const int*   iu  = (const int*)d_in[5];
    const float* su  = (const float*)d_in[6];
    const float* cbd = (const float*)d_in[7];
    const int*   idn = (const int*)d_in[8];
    const float* sd  = (const float*)d_in[9];
    float* out = (float*)d_out;

    char* p = (char*)d_ws;
    unsigned short* Xb = (unsigned short*)p; p += (size_t)TOKENS * HIDDEN * 2;
    unsigned short* Wg = (unsigned short*)p; p += (size_t)INTER * HIDDEN * 2;
    unsigned short* Wu = (unsigned short*)p; p += (size_t)INTER * HIDDEN * 2;
    unsigned short* Wd = (unsigned short*)p; p += (size_t)HIDDEN * INTER * 2;
    unsigned short* H  = (unsigned short*)p; p += (size_t)TOKENS * INTER * 2;

    prep_kernel<<<dim3(4096 + 3 * 5632), dim3(256), 0, stream>>>(
        x, Xb, ig, cbg, sg, Wg, iu, cbu, su, Wu, idn, cbd, sd, Wd);

    gemm1_kernel<<<dim3((TOKENS / BM) * (INTER / BN)), dim3(256), 0, stream>>>(Xb, Wg, Wu, H);
    gemm2_kernel<<<dim3((TOKENS / BM) * (HIDDEN / BN)), dim3(256), 0, stream>>>(H, Wd, out);
}

// Round 7
// 365.932 us; speedup vs baseline: 2.2367x; 1.0438x over previous
//
#include <hip/hip_runtime.h>

#define HIDDEN 2048
#define INTER  5632
#define TOKENS 4096

#define BM 128
#define BN 128
#define BK 64
#define GROUP_N 4

using bf16x8 = __attribute__((ext_vector_type(8))) __bf16;
using f32x4  = __attribute__((ext_vector_type(4))) float;

__device__ __forceinline__ unsigned short f2bf(float f) {
    unsigned int u = __float_as_uint(f);
    u += 0x7FFFu + ((u >> 16) & 1u);
    return (unsigned short)(u >> 16);
}

#define GLDS(gptr, lptr) \
    __builtin_amdgcn_global_load_lds((__attribute__((address_space(1))) void*)(gptr), \
                                     (__attribute__((address_space(3))) void*)(lptr), 16, 0, 0)

// ---------------- prep: dequant (LDS-cached codebook) + cast x ----------------
// blocks 0..527: dequant (176 per matrix; 8192 consecutive idx each, = exact).
// blocks 528..2575: cast x fp32->bf16 (2048 blocks x 512 thr x 8 elems).
// Codebook (4096x8 fp32 = 128KB) is converted to bf16 (64KB) in LDS once per
// block; gathers then hit LDS instead of issuing 64-way-divergent L2 reads.
__global__ __launch_bounds__(512) void prep_kernel(
        const float* __restrict__ x, unsigned short* __restrict__ xb,
        const int* __restrict__ ig, const float* __restrict__ cbg,
        const float* __restrict__ sg, unsigned short* __restrict__ wg,
        const int* __restrict__ iu, const float* __restrict__ cbu,
        const float* __restrict__ su, unsigned short* __restrict__ wu,
        const int* __restrict__ idn, const float* __restrict__ cbd,
        const float* __restrict__ sd, unsigned short* __restrict__ wd) {
    __shared__ unsigned short cbl[4096 * 8];   // 64 KB bf16 codebook
    const int b = blockIdx.x;
    const int tid = threadIdx.x;

    if (b >= 528) {                            // ---- cast x ----
        int t = (b - 528) * 512 + tid;
        const float4* x4 = (const float4*)x;
        float4 a = x4[2 * t];
        float4 c = x4[2 * t + 1];
        uint4 o;
        o.x = f2bf(a.x) | ((unsigned int)f2bf(a.y) << 16);
        o.y = f2bf(a.z) | ((unsigned int)f2bf(a.w) << 16);
        o.z = f2bf(c.x) | ((unsigned int)f2bf(c.y) << 16);
        o.w = f2bf(c.z) | ((unsigned int)f2bf(c.w) << 16);
        ((uint4*)xb)[t] = o;
        return;
    }

    // ---- dequant ----
    const int mat = b / 176;                   // 0=gate 1=up 2=down
    const int bl  = b % 176;
    const int* idx; const float* cb; const float* scale; unsigned short* w; int ncol8;
    if (mat == 0)      { idx = ig;  cb = cbg; scale = sg; w = wg; ncol8 = HIDDEN / 8; }
    else if (mat == 1) { idx = iu;  cb = cbu; scale = su; w = wu; ncol8 = HIDDEN / 8; }
    else               { idx = idn; cb = cbd; scale = sd; w = wd; ncol8 = INTER / 8; }

    // stage codebook -> LDS (bf16): thread r handles rows r, r+512, ...
#pragma unroll
    for (int i = 0; i < 8; ++i) {
        int r = i * 512 + tid;
        const float4* c4 = (const float4*)(cb + ((size_t)r << 3));
        float4 a = c4[0];
        float4 c = c4[1];
        uint4 o;
        o.x = f2bf(a.x) | ((unsigned int)f2bf(a.y) << 16);
        o.y = f2bf(a.z) | ((unsigned int)f2bf(a.w) << 16);
        o.z = f2bf(c.x) | ((unsigned int)f2bf(c.y) << 16);
        o.w = f2bf(c.z) | ((unsigned int)f2bf(c.w) << 16);
        ((uint4*)cbl)[r] = o;
    }
    __syncthreads();

    const size_t base = (size_t)bl * 8192;
#pragma unroll 2
    for (int i = 0; i < 16; ++i) {
        size_t t = base + i * 512 + tid;       // consecutive -> coalesced idx/w
        int id = idx[t];
        float s = scale[t / ncol8];
        const unsigned short* cw = cbl + ((unsigned)id << 3);
        uint4 cv = *(const uint4*)cw;          // 8 bf16
        unsigned int ww[4];
#pragma unroll
        for (int j = 0; j < 4; ++j) {
            unsigned int pair = (&cv.x)[j];
            float lo = __uint_as_float(pair << 16) * s;
            float hi = __uint_as_float(pair & 0xFFFF0000u) * s;
            ww[j] = f2bf(lo) | ((unsigned int)f2bf(hi) << 16);
        }
        uint4 o = {ww[0], ww[1], ww[2], ww[3]};
        ((uint4*)w)[t] = o;
    }
}

// XOR-swizzled LDS layout (R2-verified: SQ_LDS_BANK_CONFLICT == 0):
// physical 16B chunk p of row r holds logical chunk p ^ (r & 7); swizzle is
// applied on the GLOBAL source so the glds LDS dest stays lane-contiguous.

// group-major block decode (R5-verified: FETCH 205->144 MB)
__device__ __forceinline__ void decode_block(int bid, int nblocks_n, int* mb, int* nb) {
    int gw = 32 * GROUP_N;
    int group = bid / gw;
    int inb = bid % gw;
    int gn = group * GROUP_N;
    int width = (nblocks_n - gn < GROUP_N) ? (nblocks_n - gn) : GROUP_N;
    *mb = inb / width;
    *nb = gn + inb % width;
}

// ---------------- GEMM1: H = silu(X Wg^T) * (X Wu^T), bf16 out ----------------
// R5 structure (known-good): single LDS buffer, 2 barriers/kt, 2 blocks/CU.
// (R3: (256,3) spills acc to scratch; R4: BK=32 dbuf regressed; R6: barrier-
// free glds->ds_read is NOT hazard-safe. Do not revisit.)
__global__ __launch_bounds__(256, 2) void gemm1_kernel(const unsigned short* __restrict__ X,
                                                       const unsigned short* __restrict__ Wg,
                                                       const unsigned short* __restrict__ Wu,
                                                       unsigned short* __restrict__ H) {
    __shared__ unsigned short As[BM * BK];
    __shared__ unsigned short Bgs[BN * BK];
    __shared__ unsigned short Bus[BN * BK];

    const int tid  = threadIdx.x;
    const int lane = tid & 63;
    const int wave = tid >> 6;
    int mb, nb;
    decode_block(blockIdx.x, INTER / BN, &mb, &nb);
    const int m0 = mb * BM;
    const int n0 = nb * BN;

    const int srow = tid >> 3;
    const int scol = (tid & 7) << 3;
    const int gcol = (((tid & 7) ^ (srow & 7))) << 3;

    const int wr = wave >> 1;
    const int wc = wave & 1;
    const int ln15 = lane & 15;
    const int lq = lane >> 4;
    const int swr = ln15 & 7;

    f32x4 accg[4][4], accu[4][4];
    const f32x4 z = {0.f, 0.f, 0.f, 0.f};
    for (int i = 0; i < 4; ++i)
        for (int j = 0; j < 4; ++j) { accg[i][j] = z; accu[i][j] = z; }

    for (int kt = 0; kt < HIDDEN / BK; ++kt) {
        const int k0 = kt * BK;
        __syncthreads();
#pragma unroll
        for (int i = 0; i < 4; ++i) {
            const int r = i * 32 + srow;
            GLDS(X  + (size_t)(m0 + r) * HIDDEN + k0 + gcol, As  + r * BK + scol);
            GLDS(Wg + (size_t)(n0 + r) * HIDDEN + k0 + gcol, Bgs + r * BK + scol);
            GLDS(Wu + (size_t)(n0 + r) * HIDDEN + k0 + gcol, Bus + r * BK + scol);
        }
        __syncthreads();
#pragma unroll
        for (int ks = 0; ks < 2; ++ks) {
            bf16x8 af[4], bg[4], bu[4];
            const int pofs = (((ks * 4 + lq) ^ swr)) << 3;
#pragma unroll
            for (int im = 0; im < 4; ++im)
                af[im] = *(const bf16x8*)(As + (wr * 64 + im * 16 + ln15) * BK + pofs);
#pragma unroll
            for (int in = 0; in < 4; ++in) {
                bg[in] = *(const bf16x8*)(Bgs + (wc * 64 + in * 16 + ln15) * BK + pofs);
                bu[in] = *(const bf16x8*)(Bus + (wc * 64 + in * 16 + ln15) * BK + pofs);
            }
#pragma unroll
            for (int im = 0; im < 4; ++im)
#pragma unroll
                for (int in = 0; in < 4; ++in) {
                    accg[im][in] = __builtin_amdgcn_mfma_f32_16x16x32_bf16(af[im], bg[in], accg[im][in], 0, 0, 0);
                    accu[im][in] = __builtin_amdgcn_mfma_f32_16x16x32_bf16(af[im], bu[in], accu[im][in], 0, 0, 0);
                }
        }
    }

#pragma unroll
    for (int im = 0; im < 4; ++im)
#pragma unroll
        for (int in = 0; in < 4; ++in) {
            const int row = m0 + wr * 64 + im * 16 + lq * 4;
            const int col = n0 + wc * 64 + in * 16 + ln15;
#pragma unroll
            for (int r = 0; r < 4; ++r) {
                float g = accg[im][in][r];
                float u = accu[im][in][r];
                float h = g * (1.0f / (1.0f + __expf(-g))) * u;
                H[(size_t)(row + r) * INTER + col] = f2bf(h);
            }
        }
}

// ---------------- GEMM2: Out = H Wd^T, fp32 out ----------------
__global__ __launch_bounds__(256, 2) void gemm2_kernel(const unsigned short* __restrict__ Hin,
                                                       const unsigned short* __restrict__ Wd,
                                                       float* __restrict__ Out) {
    __shared__ unsigned short As[BM * BK];
    __shared__ unsigned short Bs[BN * BK];

    const int tid  = threadIdx.x;
    const int lane = tid & 63;
    const int wave = tid >> 6;
    int mb, nb;
    decode_block(blockIdx.x, HIDDEN / BN, &mb, &nb);
    const int m0 = mb * BM;
    const int n0 = nb * BN;

    const int srow = tid >> 3;
    const int scol = (tid & 7) << 3;
    const int gcol = (((tid & 7) ^ (srow & 7))) << 3;

    const int wr = wave >> 1;
    const int wc = wave & 1;
    const int ln15 = lane & 15;
    const int lq = lane >> 4;
    const int swr = ln15 & 7;

    f32x4 acc[4][4];
    const f32x4 z = {0.f, 0.f, 0.f, 0.f};
    for (int i = 0; i < 4; ++i)
        for (int j = 0; j < 4; ++j) acc[i][j] = z;

    for (int kt = 0; kt < INTER / BK; ++kt) {
        const int k0 = kt * BK;
        __syncthreads();
#pragma unroll
        for (int i = 0; i < 4; ++i) {
            const int r = i * 32 + srow;
            GLDS(Hin + (size_t)(m0 + r) * INTER + k0 + gcol, As + r * BK + scol);
            GLDS(Wd  + (size_t)(n0 + r) * INTER + k0 + gcol, Bs + r * BK + scol);
        }
        __syncthreads();
#pragma unroll
        for (int ks = 0; ks < 2; ++ks) {
            bf16x8 af[4], bf[4];
            const int pofs = (((ks * 4 + lq) ^ swr)) << 3;
#pragma unroll
            for (int im = 0; im < 4; ++im)
                af[im] = *(const bf16x8*)(As + (wr * 64 + im * 16 + ln15) * BK + pofs);
#pragma unroll
            for (int in = 0; in < 4; ++in)
                bf[in] = *(const bf16x8*)(Bs + (wc * 64 + in * 16 + ln15) * BK + pofs);
#pragma unroll
            for (int im = 0; im < 4; ++im)
#pragma unroll
                for (int in = 0; in < 4; ++in)
                    acc[im][in] = __builtin_amdgcn_mfma_f32_16x16x32_bf16(af[im], bf[in], acc[im][in], 0, 0, 0);
        }
    }

#pragma unroll
    for (int im = 0; im < 4; ++im)
#pragma unroll
        for (int in = 0; in < 4; ++in) {
            const int row = m0 + wr * 64 + im * 16 + lq * 4;
            const int col = n0 + wc * 64 + in * 16 + ln15;
#pragma unroll
            for (int r = 0; r < 4; ++r)
                Out[(size_t)(row + r) * HIDDEN + col] = acc[im][in][r];
        }
}

extern "C" void kernel_launch(void* const* d_in, const int* in_sizes, int n_in,
                              void* d_out, int out_size, void* d_ws, size_t ws_size,
                              hipStream_t stream) {
    (void)in_sizes; (void)n_in; (void)out_size; (void)ws_size;

    const float* x   = (const float*)d_in[0];
    const float* cbg = (const float*)d_in[1];
    const int*   ig  = (const int*)d_in[2];
    const float* sg  = (const float*)d_in[3];
    const float* cbu = (const float*)d_in[4];
    const int*   iu  = (const int*)d_in[5];
    const float* su  = (const float*)d_in[6];
    const float* cbd = (const float*)d_in[7];
    const int*   idn = (const int*)d_in[8];
    const float* sd  = (const float*)d_in[9];
    float* out = (float*)d_out;

    char* p = (char*)d_ws;
    unsigned short* Xb = (unsigned short*)p; p += (size_t)TOKENS * HIDDEN * 2;
    unsigned short* Wg = (unsigned short*)p; p += (size_t)INTER * HIDDEN * 2;
    unsigned short* Wu = (unsigned short*)p; p += (size_t)INTER * HIDDEN * 2;
    unsigned short* Wd = (unsigned short*)p; p += (size_t)HIDDEN * INTER * 2;
    unsigned short* H  = (unsigned short*)p; p += (size_t)TOKENS * INTER * 2;

    // 528 dequant blocks (176/matrix x 8192 idx) + 2048 cast blocks
    prep_kernel<<<dim3(528 + 2048), dim3(512), 0, stream>>>(
        x, Xb, ig, cbg, sg, Wg, iu, cbu, su, Wu, idn, cbd, sd, Wd);

    gemm1_kernel<<<dim3((TOKENS / BM) * (INTER / BN)), dim3(256), 0, stream>>>(Xb, Wg, Wu, H);
    gemm2_kernel<<<dim3((TOKENS / BM) * (HIDDEN / BN)), dim3(256), 0, stream>>>(H, Wd, out);
}